// Round 6
// baseline (321.337 us; speedup 1.0000x reference)
//
#include <hip/hip_runtime.h>
#include <hip/hip_fp16.h>
#include <math.h>

#define LRELU_ALPHA 0.2f
#define NEG_INF -1000000000.0f

constexpr int B_ = 8, N_ = 2048, FIN = 128, FOUT = 64;

typedef _Float16 __attribute__((ext_vector_type(8))) f16x8;
typedef float __attribute__((ext_vector_type(4))) f32x4;

// async global->LDS: lds dest = wave-uniform base, HW appends lane*16
__device__ __forceinline__ void gload16(const void* g, void* l) {
  __builtin_amdgcn_global_load_lds(
      (const __attribute__((address_space(1))) void*)g,
      (__attribute__((address_space(3))) void*)l, 16, 0, 0);
}

// ---------------------------------------------------------------------------
// Kernel 0: pack adj int32 -> 1 bit. Pure barrier-free stream; 8 int4 loads
// in flight per thread -> fillBuffer-class HBM BW. word g bit k = adj[g*32+k].
// ---------------------------------------------------------------------------
__global__ __launch_bounds__(256) void k_pack(const int* __restrict__ adj,
                                              unsigned int* __restrict__ bits) {
  const size_t g = (size_t)blockIdx.x * 256 + threadIdx.x;  // word index
  const int4* src = (const int4*)adj + g * 8;
  int4 v[8];
#pragma unroll
  for (int c = 0; c < 8; ++c) v[c] = src[c];  // all 8 issued before any use
  unsigned int w = 0;
#pragma unroll
  for (int c = 0; c < 8; ++c) {
    w |= (v[c].x != 0 ? 1u : 0u) << (c * 4 + 0);
    w |= (v[c].y != 0 ? 1u : 0u) << (c * 4 + 1);
    w |= (v[c].z != 0 ? 1u : 0u) << (c * 4 + 2);
    w |= (v[c].w != 0 ? 1u : 0u) << (c * 4 + 3);
  }
  bits[g] = w;
}

// ---------------------------------------------------------------------------
// Kernel 1: Wh = h @ W^T (fp32), emitted fp16 transposed WhT[b][o][n];
// s1 = Wh@a1, s2 = Wh@a2 (fp32). ~4 us.
// ---------------------------------------------------------------------------
__global__ __launch_bounds__(256) void k_wh(
    const float* __restrict__ h, const float* __restrict__ W,
    const float* __restrict__ a, unsigned short* __restrict__ WhT,
    float* __restrict__ s1, float* __restrict__ s2) {
  __shared__ float Wt[128][65];  // [f][o]: read bank (f+o)%32 -> conflict-free
  __shared__ float hs[16][128];

  const int t = threadIdx.x;
  const int row0 = blockIdx.x * 16;

  for (int e = t; e < 64 * 128; e += 256) {
    int o = e >> 7, f = e & 127;
    Wt[f][o] = W[e];
  }
  {
    const float4* hg = (const float4*)(h + (size_t)row0 * FIN);
    for (int i4 = t; i4 < 16 * 32; i4 += 256) {
      int r = i4 >> 5, f4 = i4 & 31;
      *(float4*)&hs[r][f4 * 4] = hg[i4];
    }
  }
  __syncthreads();

  const int wave = t >> 6, lane = t & 63;  // lane = o
  float acc[4] = {0.f, 0.f, 0.f, 0.f};
#pragma unroll 4
  for (int f4 = 0; f4 < 32; ++f4) {
    float w0 = Wt[4 * f4 + 0][lane], w1 = Wt[4 * f4 + 1][lane];
    float w2 = Wt[4 * f4 + 2][lane], w3 = Wt[4 * f4 + 3][lane];
#pragma unroll
    for (int r = 0; r < 4; ++r) {
      float4 hv = *(const float4*)&hs[wave * 4 + r][f4 * 4];
      acc[r] += hv.x * w0 + hv.y * w1 + hv.z * w2 + hv.w * w3;
    }
  }

  const float a1v = a[lane], a2v = a[64 + lane];
  const int b = row0 / N_;
#pragma unroll
  for (int r = 0; r < 4; ++r) {
    const int row = row0 + wave * 4 + r;
    const int n = row - b * N_;
    const float v = acc[r];
    WhT[((size_t)b * 64 + lane) * N_ + n] = __half_as_ushort(__float2half(v));
    float p1 = v * a1v, p2 = v * a2v;
#pragma unroll
    for (int d = 32; d; d >>= 1) {
      p1 += __shfl_xor(p1, d, 64);
      p2 += __shfl_xor(p2, d, 64);
    }
    if (lane == 0) { s1[row] = p1; s2[row] = p2; }
  }
}

// ---------------------------------------------------------------------------
// Kernel 2: masked softmax + att@Wh, all inputs L2-resident after k_pack.
// Block = 32 i-rows (grid 512 = 2/CU), chunk = 128 j (16 chunks).
// Per chunk: 16 KB WhT staged by 16 global_load_lds_dwordx4 (4/wave),
// double-buffered. Wave w: rg = w&1 (row half), oh = w>>1 (o half) -> each
// wave owns its full output tile, no cross-wave merge; exp dup 2x (oh pair).
// adj bits: 16 words/lane preloaded to VGPRs at prologue (row rg*16+m,
// word c*4+q); at K-step ks the word for (row m, ks) comes from lane
// ks*16+m via __shfl. K-loop fully unrolled so bw[c] stays static.
// p = exp(lrelu(s1+s2) - 2) keeps p in fp16 range (ratios exact).
// ---------------------------------------------------------------------------
__global__ __launch_bounds__(256, 2) void k_attn(
    const unsigned short* __restrict__ WhT,
    const float* __restrict__ s1g, const float* __restrict__ s2g,
    const unsigned int* __restrict__ bits, float* __restrict__ out) {
  __shared__ __align__(16) unsigned char sA[16 * 1024];
  __shared__ __align__(16) unsigned char sB[16 * 1024];
  __shared__ float s2s[N_];  // 8 KB

  const int t = threadIdx.x;
  const int wave = t >> 6, lane = t & 63;
  const int m = lane & 15, q = lane >> 4;
  const int b = blockIdx.y;
  const int i0 = blockIdx.x * 32;
  const int rg = wave & 1;   // row half (rows rg*16 .. +16)
  const int oh = wave >> 1;  // o half (o-groups {2oh, 2oh+1})

  const unsigned short* whB = WhT + (size_t)b * 64 * N_;

  // preload full s2 row (8 KB)
  {
    const float4* s2R = (const float4*)(s2g + b * N_);
    ((float4*)s2s)[t] = s2R[t];
    ((float4*)s2s)[256 + t] = s2R[256 + t];
  }

  const float s1r = s1g[b * N_ + i0 + rg * 16 + m];

  // prologue: all 16 bit-words for this lane's row, in flight together
  const unsigned int* bitsrow =
      bits + ((size_t)b * N_ + i0 + rg * 16 + m) * (N_ / 32);
  unsigned int bw[16];
#pragma unroll
  for (int c = 0; c < 16; ++c) bw[c] = bitsrow[c * 4 + q];

  // staging: wave w stages o-group g=w, 4 K-step slots; slot (g,ks) holds
  // WhT[g*16+m'][c*128 + ks*32 + q'*8 ..+8] at lane position q'*16+m'.
  const unsigned char* gp[4];
#pragma unroll
  for (int ks = 0; ks < 4; ++ks)
    gp[ks] = (const unsigned char*)(whB + (size_t)(wave * 16 + m) * N_ +
                                    ks * 32 + q * 8);

#define STAGE(S, c)                                                     \
  {                                                                     \
    _Pragma("unroll") for (int ks = 0; ks < 4; ++ks)                    \
        gload16(gp[ks] + (size_t)(c) * 256, (S) + (wave * 4 + ks) * 1024); \
  }

  f32x4 acc0 = {0.f, 0.f, 0.f, 0.f}, acc1 = acc0;
  float lsum = 0.f;

  auto consume = [&](const unsigned char* base, unsigned int word, int c) {
#pragma unroll
    for (int ks = 0; ks < 4; ++ks) {
      // word (c*4+ks) of row (rg*16+m) lives in lane ks*16+m's 'word'
      unsigned int ws = __shfl((int)word, ks * 16 + m, 64);
      const float* sp = &s2s[c * 128 + ks * 32 + q * 8];
      float4 sv0 = *(const float4*)sp;
      float4 sv1 = *(const float4*)(sp + 4);
      float xs[8] = {sv0.x, sv0.y, sv0.z, sv0.w, sv1.x, sv1.y, sv1.z, sv1.w};
      f16x8 af;
#pragma unroll
      for (int j = 0; j < 8; ++j) {
        float x = s1r + xs[j];
        float e = fmaxf(x, LRELU_ALPHA * x);
        e = ((ws >> (q * 8 + j)) & 1u) ? (e - 2.0f) : NEG_INF;
        float p = __expf(e);  // masked -> exactly 0.0f
        lsum += p;
        af[j] = (_Float16)p;
      }
      f16x8 b0 = *(const f16x8*)(base + ((2 * oh + 0) * 4 + ks) * 1024 + lane * 16);
      f16x8 b1 = *(const f16x8*)(base + ((2 * oh + 1) * 4 + ks) * 1024 + lane * 16);
      acc0 = __builtin_amdgcn_mfma_f32_16x16x32_f16(af, b0, acc0, 0, 0, 0);
      acc1 = __builtin_amdgcn_mfma_f32_16x16x32_f16(af, b1, acc1, 0, 0, 0);
    }
  };

  STAGE(sA, 0);
  __syncthreads();  // chunk 0 staged + s2s visible

#pragma unroll
  for (int cc = 0; cc < 8; ++cc) {
    const int c0 = 2 * cc, c1 = 2 * cc + 1;
    STAGE(sB, c1);
    consume(sA, bw[c0], c0);
    __syncthreads();
    if (c1 + 1 < 16) STAGE(sA, c1 + 1);
    consume(sB, bw[c1], c1);
    __syncthreads();
  }

  // epilogue: row sums (full dup across oh waves -> no merge needed)
  lsum += __shfl_xor(lsum, 16, 64);
  lsum += __shfl_xor(lsum, 32, 64);  // all q-copies now hold row(rg*16+m) sum

  // C/D layout: row_in_tile = q*4 + r, col = m
#pragma unroll
  for (int r = 0; r < 4; ++r) {
    const int ri = q * 4 + r;
    float l = __shfl(lsum, ri, 64);  // lane (m=ri, q=0) holds row ri's sum
    float inv = (l == 0.f) ? 1.f : 1.f / l;  // fully-masked row guard
    const size_t row = (size_t)b * N_ + i0 + rg * 16 + ri;
    out[row * FOUT + (2 * oh + 0) * 16 + m] = acc0[r] * inv;
    out[row * FOUT + (2 * oh + 1) * 16 + m] = acc1[r] * inv;
  }
#undef STAGE
}

extern "C" void kernel_launch(void* const* d_in, const int* in_sizes, int n_in,
                              void* d_out, int out_size, void* d_ws, size_t ws_size,
                              hipStream_t stream) {
  const float* h   = (const float*)d_in[0];
  const int*   adj = (const int*)d_in[1];
  const float* W   = (const float*)d_in[2];
  const float* a   = (const float*)d_in[3];
  float* out = (float*)d_out;

  // ws: WhT fp16 (2 MB) | s1 (64 KB) | s2 (64 KB) | bits (4 MB)
  unsigned short* WhT = (unsigned short*)d_ws;
  float* s1 = (float*)(WhT + (size_t)B_ * 64 * N_);
  float* s2 = s1 + (size_t)B_ * N_;
  unsigned int* bits = (unsigned int*)(s2 + (size_t)B_ * N_);

  const int nwords = B_ * N_ * (N_ / 32);  // 1,048,576
  k_pack<<<dim3(nwords / 256), 256, 0, stream>>>(adj, bits);
  k_wh<<<dim3(B_ * N_ / 16), 256, 0, stream>>>(h, W, a, WhT, s1, s2);
  k_attn<<<dim3(N_ / 32, B_), 256, 0, stream>>>(WhT, s1, s2, bits, out);
}

// Round 7
// 244.400 us; speedup vs baseline: 1.3148x; 1.3148x over previous
//
#include <hip/hip_runtime.h>
#include <hip/hip_fp16.h>
#include <math.h>

#define LRELU_ALPHA 0.2f

constexpr int B_ = 8, N_ = 2048, FIN = 128, FOUT = 64;

typedef _Float16 f16x2 __attribute__((ext_vector_type(2)));
typedef _Float16 f16x8 __attribute__((ext_vector_type(8)));
typedef float f32x4 __attribute__((ext_vector_type(4)));

__device__ __forceinline__ unsigned short f2h(float x) {
  return __half_as_ushort(__float2half(x));
}

// ---------------------------------------------------------------------------
// Kernel 0: pack adj int32 -> 1 bit (validated R6). Barrier-free stream at
// ~fillBuffer BW. word g bit k = adj[g*32+k] != 0.
// ---------------------------------------------------------------------------
__global__ __launch_bounds__(256) void k_pack(const int* __restrict__ adj,
                                              unsigned int* __restrict__ bits) {
  const size_t g = (size_t)blockIdx.x * 256 + threadIdx.x;
  const int4* src = (const int4*)adj + g * 8;
  int4 v[8];
#pragma unroll
  for (int c = 0; c < 8; ++c) v[c] = src[c];
  unsigned int w = 0;
#pragma unroll
  for (int c = 0; c < 8; ++c) {
    w |= (v[c].x != 0 ? 1u : 0u) << (c * 4 + 0);
    w |= (v[c].y != 0 ? 1u : 0u) << (c * 4 + 1);
    w |= (v[c].z != 0 ? 1u : 0u) << (c * 4 + 2);
    w |= (v[c].w != 0 ? 1u : 0u) << (c * 4 + 3);
  }
  bits[g] = w;
}

// ---------------------------------------------------------------------------
// Kernel 1: Wh = h@W^T (fp32) -> WhT fp16 [b][o][n]; plus separable-exp
// factors: e1th[i] = {E1p=exp(s1-1), E1n=exp(.2*s1-1), T=exp(-1-s1)} (f16),
// e2h2[j] = {E2p=exp(s2-1), E2n=exp(.2*s2-1)} (f16x2).
// x>0 test later: E2p(j) > T(i)  <=>  s1+s2 > 0 (monotone).
// ---------------------------------------------------------------------------
__global__ __launch_bounds__(256) void k_wh(
    const float* __restrict__ h, const float* __restrict__ W,
    const float* __restrict__ a, unsigned short* __restrict__ WhT,
    ushort4* __restrict__ e1th, unsigned int* __restrict__ e2h2) {
  __shared__ float Wt[128][65];  // [f][o]: bank (f+o)%32 -> conflict-free
  __shared__ float hs[16][128];

  const int t = threadIdx.x;
  const int row0 = blockIdx.x * 16;

  for (int e = t; e < 64 * 128; e += 256) {
    int o = e >> 7, f = e & 127;
    Wt[f][o] = W[e];
  }
  {
    const float4* hg = (const float4*)(h + (size_t)row0 * FIN);
    for (int i4 = t; i4 < 16 * 32; i4 += 256) {
      int r = i4 >> 5, f4 = i4 & 31;
      *(float4*)&hs[r][f4 * 4] = hg[i4];
    }
  }
  __syncthreads();

  const int wave = t >> 6, lane = t & 63;  // lane = o
  float acc[4] = {0.f, 0.f, 0.f, 0.f};
#pragma unroll 4
  for (int f4 = 0; f4 < 32; ++f4) {
    float w0 = Wt[4 * f4 + 0][lane], w1 = Wt[4 * f4 + 1][lane];
    float w2 = Wt[4 * f4 + 2][lane], w3 = Wt[4 * f4 + 3][lane];
#pragma unroll
    for (int r = 0; r < 4; ++r) {
      float4 hv = *(const float4*)&hs[wave * 4 + r][f4 * 4];
      acc[r] += hv.x * w0 + hv.y * w1 + hv.z * w2 + hv.w * w3;
    }
  }

  const float a1v = a[lane], a2v = a[64 + lane];
  const int b = row0 / N_;
#pragma unroll
  for (int r = 0; r < 4; ++r) {
    const int row = row0 + wave * 4 + r;  // = b*N + n
    const int n = row - b * N_;
    const float v = acc[r];
    WhT[((size_t)b * 64 + lane) * N_ + n] = f2h(v);
    float p1 = v * a1v, p2 = v * a2v;
#pragma unroll
    for (int d = 32; d; d >>= 1) {  // butterfly all-reduce
      p1 += __shfl_xor(p1, d, 64);
      p2 += __shfl_xor(p2, d, 64);
    }
    if (lane == 0) {
      ushort4 e1;
      e1.x = f2h(__expf(p1 - 1.0f));
      e1.y = f2h(__expf(LRELU_ALPHA * p1 - 1.0f));
      e1.z = f2h(__expf(-1.0f - p1));
      e1.w = 0;
      e1th[row] = e1;
      e2h2[row] = (unsigned int)f2h(__expf(p2 - 1.0f)) |
                  ((unsigned int)f2h(__expf(LRELU_ALPHA * p2 - 1.0f)) << 16);
    }
  }
}

// ---------------------------------------------------------------------------
// Kernel 2: LDS-resident attention. Block = (b, j-eighth 256, full 64 o,
// i-range 256). WhT tile (32 KB, f16) loaded to LDS ONCE, XOR-swizzled
// 16B chunks (chunk c of row o at c^(o&31)) -> B-frag ds_read_b128 is
// 2-way/free per 16-lane phase. K-loop has NO large global traffic:
// per i-tile only e1th (8B) + bits (8B) per lane, L2-hot.
// p = select(E2p>T, E1p*E2p, E1n*E2n) masked by adj bit -> one v_pk_mul_f16,
// no exp. lsum via 5th MFMA against a ones-fragment. 4 waves split j-strip
// (64 each); j-partials (fp32) written to ws, merged by k_reduce.
// i-loop rolled (unroll 1) -- R6's full unroll blew the I-cache.
// ---------------------------------------------------------------------------
__global__ __launch_bounds__(256, 2) void k_attn(
    const unsigned short* __restrict__ WhT,
    const ushort4* __restrict__ e1th, const unsigned int* __restrict__ e2h2,
    const unsigned int* __restrict__ bits,
    float* __restrict__ pa, float* __restrict__ ls) {
  __shared__ __align__(16) unsigned short whs[64 * 256];  // 32 KB swizzled
  __shared__ unsigned int e2s[256];                       // 1 KB
  __shared__ float accm[4][64][20];                       // 20 KB merge buf

  const int t = threadIdx.x;
  const int wv = t >> 6, lane = t & 63;
  const int m = lane & 15, q = lane >> 4;
  const int ir = blockIdx.x, jw = blockIdx.y, b = blockIdx.z;
  const int i0 = ir * 256, jw0 = jw * 256;

  // ---- one-time LDS fill ----
  const unsigned short* whB = WhT + (size_t)b * 64 * N_ + jw0;
#pragma unroll
  for (int l = 0; l < 8; ++l) {
    int id = l * 256 + t;
    int o = id >> 5, c = id & 31;
    uint4 v = *(const uint4*)(whB + (size_t)o * N_ + c * 8);
    int sc = c ^ (o & 31);
    *(uint4*)&whs[o * 256 + sc * 8] = v;
  }
  e2s[t] = e2h2[b * N_ + jw0 + t];
  __syncthreads();

  // i-independent LDS byte offsets for the 8 B-fragments
  int boff[2][4];
#pragma unroll
  for (int ks = 0; ks < 2; ++ks)
#pragma unroll
    for (int g = 0; g < 4; ++g) {
      int o = g * 16 + m;
      int c = wv * 8 + ks * 4 + q;
      boff[ks][g] = o * 512 + ((c ^ (o & 31)) << 4);
    }
  const int e2base0 = wv * 64 + q * 8;

  const f16x8 ones = {1, 1, 1, 1, 1, 1, 1, 1};

#pragma unroll 1
  for (int it = 0; it < 16; ++it) {
    const int row = i0 + it * 16 + m;  // this lane's A-row
    const ushort4 e1u = e1th[b * N_ + row];
    const uint2 w2 =
        *(const uint2*)(bits + ((size_t)(b * N_ + row)) * 64 + jw * 8 + wv * 2);
    const f16x2 e1p2 = __builtin_bit_cast(
        f16x2, (unsigned int)e1u.x | ((unsigned int)e1u.y << 16));
    const _Float16 Tf = __builtin_bit_cast(_Float16, (unsigned short)e1u.z);

    f32x4 ac0 = {0.f, 0.f, 0.f, 0.f}, ac1 = ac0, ac2 = ac0, ac3 = ac0, lf = ac0;

#pragma unroll
    for (int ks = 0; ks < 2; ++ks) {
      const unsigned int word = (ks ? w2.y : w2.x) >> (q * 8);
      const uint4* ep = (const uint4*)&e2s[e2base0 + ks * 32];
      const uint4 E0 = ep[0], E1v = ep[1];
      const unsigned int eu[8] = {E0.x, E0.y, E0.z, E0.w,
                                  E1v.x, E1v.y, E1v.z, E1v.w};
      f16x8 af;
#pragma unroll
      for (int jj = 0; jj < 8; ++jj) {
        f16x2 e2p = __builtin_bit_cast(f16x2, eu[jj]);
        f16x2 pr = e1p2 * e2p;                          // v_pk_mul_f16
        _Float16 ps = (e2p.x > Tf) ? pr.x : pr.y;       // branch select
        ps = ((word >> jj) & 1u) ? ps : (_Float16)0.0f; // adj mask
        af[jj] = ps;
      }
      f16x8 b0 = *(const f16x8*)((const char*)whs + boff[ks][0]);
      f16x8 b1 = *(const f16x8*)((const char*)whs + boff[ks][1]);
      f16x8 b2 = *(const f16x8*)((const char*)whs + boff[ks][2]);
      f16x8 b3 = *(const f16x8*)((const char*)whs + boff[ks][3]);
      ac0 = __builtin_amdgcn_mfma_f32_16x16x32_f16(af, b0, ac0, 0, 0, 0);
      ac1 = __builtin_amdgcn_mfma_f32_16x16x32_f16(af, b1, ac1, 0, 0, 0);
      ac2 = __builtin_amdgcn_mfma_f32_16x16x32_f16(af, b2, ac2, 0, 0, 0);
      ac3 = __builtin_amdgcn_mfma_f32_16x16x32_f16(af, b3, ac3, 0, 0, 0);
      lf  = __builtin_amdgcn_mfma_f32_16x16x32_f16(af, ones, lf, 0, 0, 0);
    }

    // ---- merge 4 waves' j-partials via LDS, write fp32 partial tile ----
    {
      float* al = &accm[wv][lane][0];
      *(f32x4*)(al + 0) = ac0;
      *(f32x4*)(al + 4) = ac1;
      *(f32x4*)(al + 8) = ac2;
      *(f32x4*)(al + 12) = ac3;
      *(f32x4*)(al + 16) = lf;
    }
    __syncthreads();
    {
      const int ri = t >> 4, c4 = t & 15;
      const int g = c4 >> 2, qq = ri >> 2, rr = ri & 3;
      float4 s = {0.f, 0.f, 0.f, 0.f};
#pragma unroll
      for (int w = 0; w < 4; ++w) {
        const int lbase = qq * 16 + (c4 & 3) * 4;
        s.x += accm[w][lbase + 0][g * 4 + rr];
        s.y += accm[w][lbase + 1][g * 4 + rr];
        s.z += accm[w][lbase + 2][g * 4 + rr];
        s.w += accm[w][lbase + 3][g * 4 + rr];
      }
      const size_t oidx = (size_t)jw * 1048576 +
                          ((size_t)(b * N_ + i0 + it * 16 + ri)) * 64 + c4 * 4;
      *(float4*)&pa[oidx] = s;
      if (t < 16) {
        float l = 0.f;
#pragma unroll
        for (int w = 0; w < 4; ++w) l += accm[w][(t >> 2) * 16][16 + (t & 3)];
        ls[jw * 16384 + b * N_ + i0 + it * 16 + t] = l;
      }
    }
    __syncthreads();  // accm reuse next i-tile
  }
}

// ---------------------------------------------------------------------------
// Kernel 3: out = (sum_jw pa) / (sum_jw ls). 36 MB stream, ~6 us.
// ---------------------------------------------------------------------------
__global__ __launch_bounds__(256) void k_reduce(const float* __restrict__ pa,
                                                const float* __restrict__ ls,
                                                float* __restrict__ out) {
  const size_t e = (size_t)blockIdx.x * 256 + threadIdx.x;
  const int ifl = (int)(e >> 6);
  float s = 0.f, l = 0.f;
#pragma unroll
  for (int jw = 0; jw < 8; ++jw) {
    s += pa[(size_t)jw * 1048576 + e];
    l += ls[jw * 16384 + ifl];
  }
  out[e] = s / (l == 0.f ? 1.f : l);  // fully-masked row guard
}

extern "C" void kernel_launch(void* const* d_in, const int* in_sizes, int n_in,
                              void* d_out, int out_size, void* d_ws, size_t ws_size,
                              hipStream_t stream) {
  const float* h   = (const float*)d_in[0];
  const int*   adj = (const int*)d_in[1];
  const float* W   = (const float*)d_in[2];
  const float* a   = (const float*)d_in[3];
  float* out = (float*)d_out;

  // ws: WhT 2MB | e1th 128KB | e2h2 64KB | bits 4MB | pa 32MB | ls 512KB
  unsigned short* WhT = (unsigned short*)d_ws;
  ushort4* e1th = (ushort4*)(WhT + (size_t)B_ * 64 * N_);
  unsigned int* e2h2 = (unsigned int*)(e1th + B_ * N_);
  unsigned int* bits = (unsigned int*)(e2h2 + B_ * N_);
  float* pa = (float*)(bits + (size_t)B_ * N_ * (N_ / 32));
  float* ls = pa + (size_t)8 * 1048576;

  const int nwords = B_ * N_ * (N_ / 32);  // 1,048,576
  k_pack<<<dim3(nwords / 256), 256, 0, stream>>>(adj, bits);
  k_wh<<<dim3(B_ * N_ / 16), 256, 0, stream>>>(h, W, a, WhT, e1th, e2h2);
  k_attn<<<dim3(8, 8, 8), 256, 0, stream>>>(WhT, e1th, e2h2, bits, pa, ls);
  k_reduce<<<dim3(4096), 256, 0, stream>>>(pa, ls, out);
}

// Round 8
// 238.916 us; speedup vs baseline: 1.3450x; 1.0230x over previous
//
#include <hip/hip_runtime.h>
#include <hip/hip_fp16.h>
#include <math.h>

#define LRELU_ALPHA 0.2f

constexpr int B_ = 8, N_ = 2048, FIN = 128, FOUT = 64;

typedef _Float16 f16x2 __attribute__((ext_vector_type(2)));
typedef _Float16 f16x8 __attribute__((ext_vector_type(8)));
typedef float f32x4 __attribute__((ext_vector_type(4)));

__device__ __forceinline__ unsigned short f2h(float x) {
  return __half_as_ushort(__float2half(x));
}

// ---------------------------------------------------------------------------
// Kernel 0: pack adj int32 -> 1 bit (validated). ~fillBuffer-class HBM BW.
// ---------------------------------------------------------------------------
__global__ __launch_bounds__(256) void k_pack(const int* __restrict__ adj,
                                              unsigned int* __restrict__ bits) {
  const size_t g = (size_t)blockIdx.x * 256 + threadIdx.x;
  const int4* src = (const int4*)adj + g * 8;
  int4 v[8];
#pragma unroll
  for (int c = 0; c < 8; ++c) v[c] = src[c];
  unsigned int w = 0;
#pragma unroll
  for (int c = 0; c < 8; ++c) {
    w |= (v[c].x != 0 ? 1u : 0u) << (c * 4 + 0);
    w |= (v[c].y != 0 ? 1u : 0u) << (c * 4 + 1);
    w |= (v[c].z != 0 ? 1u : 0u) << (c * 4 + 2);
    w |= (v[c].w != 0 ? 1u : 0u) << (c * 4 + 3);
  }
  bits[g] = w;
}

// ---------------------------------------------------------------------------
// Kernel 1: Wh = h@W^T (fp32) -> WhT fp16 [b][o][n]; separable-exp factors:
// e1h2[i] = pack(E1p=exp(s1-1), E1n=exp(.2*s1-1)) f16x2;
// e2ps[j] = exp(s2-1), e2ns[j] = exp(.2*s2-1) (f16).
// Later: p = exp(lrelu(s1+s2)-2) = max(E1p*E2p, E1n*E2n) (exp monotone).
// ---------------------------------------------------------------------------
__global__ __launch_bounds__(256) void k_wh(
    const float* __restrict__ h, const float* __restrict__ W,
    const float* __restrict__ a, unsigned short* __restrict__ WhT,
    unsigned int* __restrict__ e1h2, unsigned short* __restrict__ e2ps,
    unsigned short* __restrict__ e2ns) {
  __shared__ float Wt[128][65];  // [f][o]: bank (f+o)%32 -> conflict-free
  __shared__ float hs[16][128];

  const int t = threadIdx.x;
  const int row0 = blockIdx.x * 16;

  for (int e = t; e < 64 * 128; e += 256) {
    int o = e >> 7, f = e & 127;
    Wt[f][o] = W[e];
  }
  {
    const float4* hg = (const float4*)(h + (size_t)row0 * FIN);
    for (int i4 = t; i4 < 16 * 32; i4 += 256) {
      int r = i4 >> 5, f4 = i4 & 31;
      *(float4*)&hs[r][f4 * 4] = hg[i4];
    }
  }
  __syncthreads();

  const int wave = t >> 6, lane = t & 63;  // lane = o
  float acc[4] = {0.f, 0.f, 0.f, 0.f};
#pragma unroll 4
  for (int f4 = 0; f4 < 32; ++f4) {
    float w0 = Wt[4 * f4 + 0][lane], w1 = Wt[4 * f4 + 1][lane];
    float w2 = Wt[4 * f4 + 2][lane], w3 = Wt[4 * f4 + 3][lane];
#pragma unroll
    for (int r = 0; r < 4; ++r) {
      float4 hv = *(const float4*)&hs[wave * 4 + r][f4 * 4];
      acc[r] += hv.x * w0 + hv.y * w1 + hv.z * w2 + hv.w * w3;
    }
  }

  const float a1v = a[lane], a2v = a[64 + lane];
  const int b = row0 / N_;
#pragma unroll
  for (int r = 0; r < 4; ++r) {
    const int row = row0 + wave * 4 + r;  // = b*N + n
    const int n = row - b * N_;
    const float v = acc[r];
    WhT[((size_t)b * 64 + lane) * N_ + n] = f2h(v);
    float p1 = v * a1v, p2 = v * a2v;
#pragma unroll
    for (int d = 32; d; d >>= 1) {
      p1 += __shfl_xor(p1, d, 64);
      p2 += __shfl_xor(p2, d, 64);
    }
    if (lane == 0) {
      e1h2[row] = (unsigned int)f2h(__expf(p1 - 1.0f)) |
                  ((unsigned int)f2h(__expf(LRELU_ALPHA * p1 - 1.0f)) << 16);
      e2ps[row] = f2h(__expf(p2 - 1.0f));
      e2ns[row] = f2h(__expf(LRELU_ALPHA * p2 - 1.0f));
    }
  }
}

// ---------------------------------------------------------------------------
// Kernel 2: attention partials, BARRIER-FREE after the one-time LDS fill.
// Block = (b, jw 256-j strip, 256 i-rows); grid 8x8x8 = 512 = 2 blocks/CU.
// WhT strip (32 KB f16) in LDS, XOR-swizzled (chunk c of row o at c^(o&31))
// -> B-frag ds_read_b128 2-way max (free). Wave owns 4 WHOLE i-tiles
// (64 rows x full strip): per ks, 4 B-frags + 2 e2 b128 are reused across
// 4 tiles -> 20 MFMA per 6 LDS reads, no cross-wave merge, no barriers.
// e1/bits for all 4 tiles prefetched before the fill barrier.
// p = max(E1p*E2p, E1n*E2n) masked by adj bit; lsum via ones-MFMA.
// Raw fp32 j-partials -> pa; k_reduce merges 8 strips.
// ---------------------------------------------------------------------------
__global__ __launch_bounds__(256, 2) void k_attn(
    const unsigned short* __restrict__ WhT,
    const unsigned int* __restrict__ e1h2,
    const unsigned short* __restrict__ e2ps,
    const unsigned short* __restrict__ e2ns,
    const unsigned int* __restrict__ bits,
    float* __restrict__ pa, float* __restrict__ ls) {
  __shared__ __align__(16) unsigned short whs[64 * 256];  // 32 KB swizzled
  __shared__ __align__(16) unsigned short e2sp[256], e2sn[256];

  const int t = threadIdx.x;
  const int wv = t >> 6, lane = t & 63;
  const int m = lane & 15, q = lane >> 4;
  const int ir = blockIdx.x, jw = blockIdx.y, b = blockIdx.z;
  const int i0 = ir * 256, jw0 = jw * 256;

  // ---- prefetch per-wave row data (in flight across the fill) ----
  unsigned int e1u[4];
  uint4 wA[4], wB[4];  // 8 bit-words per (row, strip)
#pragma unroll
  for (int tt = 0; tt < 4; ++tt) {
    const int row = b * N_ + i0 + wv * 64 + tt * 16 + m;
    e1u[tt] = e1h2[row];
    const uint4* bp = (const uint4*)(bits + (size_t)row * 64 + jw * 8);
    wA[tt] = bp[0];
    wB[tt] = bp[1];
  }

  // ---- one-time LDS fill ----
  const unsigned short* whB = WhT + (size_t)b * 64 * N_ + jw0;
#pragma unroll
  for (int l = 0; l < 8; ++l) {
    int id = l * 256 + t;
    int o = id >> 5, c = id & 31;
    uint4 v = *(const uint4*)(whB + (size_t)o * N_ + c * 8);
    *(uint4*)&whs[o * 256 + ((c ^ (o & 31)) << 3)] = v;
  }
  e2sp[t] = e2ps[b * N_ + jw0 + t];
  e2sn[t] = e2ns[b * N_ + jw0 + t];
  __syncthreads();  // the only barrier

  f32x4 acc[4][4];  // [tile][o-group]
  f32x4 lf[4];
#pragma unroll
  for (int tt = 0; tt < 4; ++tt) {
    lf[tt] = (f32x4){0.f, 0.f, 0.f, 0.f};
#pragma unroll
    for (int g = 0; g < 4; ++g) acc[tt][g] = (f32x4){0.f, 0.f, 0.f, 0.f};
  }

  const f16x8 ones = {1, 1, 1, 1, 1, 1, 1, 1};
  const int qb = q * 8;

#pragma unroll
  for (int ks = 0; ks < 8; ++ks) {
    // B-fragments + e2, shared across the wave's 4 i-tiles
    f16x8 bfr[4];
#pragma unroll
    for (int g = 0; g < 4; ++g) {
      const int o = g * 16 + m;
      bfr[g] = *(const f16x8*)&whs[o * 256 + (((ks * 4 + q) ^ (o & 31)) << 3)];
    }
    const f16x8 e2pv = *(const f16x8*)&e2sp[ks * 32 + qb];
    const f16x8 e2nv = *(const f16x8*)&e2sn[ks * 32 + qb];

#pragma unroll
    for (int tt = 0; tt < 4; ++tt) {
      const uint4 wq4 = (ks < 4) ? wA[tt] : wB[tt];
      const unsigned int word =
          (ks & 3) == 0 ? wq4.x : (ks & 3) == 1 ? wq4.y
                        : (ks & 3) == 2 ? wq4.z : wq4.w;
      const unsigned int wq = word >> qb;
      const f16x2 e1 = __builtin_bit_cast(f16x2, e1u[tt]);
      f16x8 af;
#pragma unroll
      for (int jj = 0; jj < 8; ++jj) {
        _Float16 pp = e1.x * e2pv[jj];
        _Float16 pn = e1.y * e2nv[jj];
        _Float16 pm = pp > pn ? pp : pn;  // == exp(lrelu(s1+s2)-2)
        af[jj] = ((wq >> jj) & 1u) ? pm : (_Float16)0;
      }
      acc[tt][0] = __builtin_amdgcn_mfma_f32_16x16x32_f16(af, bfr[0], acc[tt][0], 0, 0, 0);
      acc[tt][1] = __builtin_amdgcn_mfma_f32_16x16x32_f16(af, bfr[1], acc[tt][1], 0, 0, 0);
      acc[tt][2] = __builtin_amdgcn_mfma_f32_16x16x32_f16(af, bfr[2], acc[tt][2], 0, 0, 0);
      acc[tt][3] = __builtin_amdgcn_mfma_f32_16x16x32_f16(af, bfr[3], acc[tt][3], 0, 0, 0);
      lf[tt] = __builtin_amdgcn_mfma_f32_16x16x32_f16(af, ones, lf[tt], 0, 0, 0);
    }
  }

  // ---- epilogue: raw partial stores (C-layout: row = q*4+r, col = m) ----
#pragma unroll
  for (int tt = 0; tt < 4; ++tt) {
    const int rowb = i0 + wv * 64 + tt * 16;
#pragma unroll
    for (int r = 0; r < 4; ++r) {
      const size_t off = (size_t)jw * 1048576 +
                         ((size_t)(b * N_ + rowb + q * 4 + r)) * 64;
#pragma unroll
      for (int g = 0; g < 4; ++g) pa[off + g * 16 + m] = acc[tt][g][r];
      if (m == 0)
        ls[jw * 16384 + b * N_ + rowb + q * 4 + r] = lf[tt][r];
    }
  }
}

// ---------------------------------------------------------------------------
// Kernel 3: out = (sum_jw pa) / (sum_jw ls). 36 MB stream.
// ---------------------------------------------------------------------------
__global__ __launch_bounds__(256) void k_reduce(const float* __restrict__ pa,
                                                const float* __restrict__ ls,
                                                float* __restrict__ out) {
  const size_t e = (size_t)blockIdx.x * 256 + threadIdx.x;
  const int ifl = (int)(e >> 6);
  float s = 0.f, l = 0.f;
#pragma unroll
  for (int jw = 0; jw < 8; ++jw) {
    s += pa[(size_t)jw * 1048576 + e];
    l += ls[jw * 16384 + ifl];
  }
  out[e] = s / (l == 0.f ? 1.f : l);  // fully-masked row guard
}

extern "C" void kernel_launch(void* const* d_in, const int* in_sizes, int n_in,
                              void* d_out, int out_size, void* d_ws, size_t ws_size,
                              hipStream_t stream) {
  const float* h   = (const float*)d_in[0];
  const int*   adj = (const int*)d_in[1];
  const float* W   = (const float*)d_in[2];
  const float* a   = (const float*)d_in[3];
  float* out = (float*)d_out;

  // ws: WhT 2MB | e1h2 64KB | e2ps 32KB | e2ns 32KB | bits 4MB | pa 32MB | ls 512KB
  unsigned short* WhT = (unsigned short*)d_ws;
  unsigned int* e1h2 = (unsigned int*)(WhT + (size_t)B_ * 64 * N_);
  unsigned short* e2ps = (unsigned short*)(e1h2 + B_ * N_);
  unsigned short* e2ns = e2ps + B_ * N_;
  unsigned int* bits = (unsigned int*)(e2ns + B_ * N_);
  float* pa = (float*)(bits + (size_t)B_ * N_ * (N_ / 32));
  float* ls = pa + (size_t)8 * 1048576;

  const int nwords = B_ * N_ * (N_ / 32);  // 1,048,576
  k_pack<<<dim3(nwords / 256), 256, 0, stream>>>(adj, bits);
  k_wh<<<dim3(B_ * N_ / 16), 256, 0, stream>>>(h, W, a, WhT, e1h2, e2ps, e2ns);
  k_attn<<<dim3(8, 8, 8), 256, 0, stream>>>(WhT, e1h2, e2ps, e2ns, bits, pa, ls);
  k_reduce<<<dim3(4096), 256, 0, stream>>>(pa, ls, out);
}